// Round 8
// baseline (79.416 us; speedup 1.0000x reference)
//
#include <hip/hip_runtime.h>
#include <math.h>

#define TPB 256
#define WPB (TPB / 64)   // 4 rows (waves) per block
#define EPL 64           // elements per lane (one wave owns a 4096 row)
#define COLS 4096

typedef float vfloat4 __attribute__((ext_vector_type(4)));

__device__ __forceinline__ float wave_sum(float v) {
#pragma unroll
    for (int o = 32; o > 0; o >>= 1) v += __shfl_xor(v, o, 64);
    return v;
}
__device__ __forceinline__ float wave_max(float v) {
#pragma unroll
    for (int o = 32; o > 0; o >>= 1) v = fmaxf(v, __shfl_xor(v, o, 64));
    return v;
}

// robust Halley step toward p = W(t), hardware exp (rare path only)
__device__ __forceinline__ float halley_hw(float p, float t) {
    float e = __expf(p);
    float w = p * e;
    float f = w - t;
    float fp = w + e;                                // (1+p)e
    float den = fmaf(fp, fp, -0.5f * f * (fp + e));  // fp^2 - 0.5 f (2+p)e
    return p - __fdividef(f * fp, den);
}

// Per row: p_i = W(e^{2(y_i+nu)-1}), nu s.t. sum p = 1   (alpha = 0.5)
// One wave per row: all reductions are shuffle butterflies, NO barriers/LDS.
__global__ __launch_bounds__(TPB) void prox_softmax_kernel(
    const float* __restrict__ X, float* __restrict__ P, int rows)
{
    const int lane = threadIdx.x & 63;
    const int row = blockIdx.x * WPB + (threadIdx.x >> 6);
    if (row >= rows) return;

    const float4* __restrict__ x4 = reinterpret_cast<const float4*>(X + (size_t)row * COLS);
    vfloat4* __restrict__ p4 = reinterpret_cast<vfloat4*>(P + (size_t)row * COLS);

    float q[EPL];   // y -> exp(2y) -> p  (reused in place)

    // ---- load row: 16 coalesced float4 per lane ----
#pragma unroll
    for (int j = 0; j < 16; ++j) {
        float4 v = x4[lane + j * 64];
        q[4 * j + 0] = v.x; q[4 * j + 1] = v.y;
        q[4 * j + 2] = v.z; q[4 * j + 3] = v.w;
    }

    // ---- exp pass: q = exp(2y) = exp2(y*2/ln2); A = sum q, B = sum q^2, qm = max q ----
    const float C2E = 2.8853900817779268f;  // 2/ln(2)
    float A = 0.f, B = 0.f, qm = 0.f;
#pragma unroll
    for (int j = 0; j < EPL; ++j) {
        float e = __builtin_amdgcn_exp2f(q[j] * C2E);
        q[j] = e;
        A += e;
        B = fmaf(e, e, B);
        qm = fmaxf(qm, e);
    }
    A = wave_sum(A); B = wave_sum(B); qm = wave_max(qm);

    // ---- scalar init: solve s*A - s^2*B = 1 (W series thru t^2), smaller root ----
    float disc = fmaf(A, A, -4.f * B);
    float s = __fdividef(2.f, A + sqrtf(fmaxf(disc, 0.f)));

    // ---- fast eval: W series thru t^7 (no divides); S1 = sum p, S2 = sum p/(1+p) ----
    float S1 = 0.f, S2 = 0.f;
#pragma unroll
    for (int j = 0; j < EPL; ++j) {
        float t = q[j] * s;
        float acc = fmaf(23.343054f, t, -10.8f);      // c7, c6
        acc = fmaf(acc, t, 125.f / 24.f);             // c5
        acc = fmaf(acc, t, -8.f / 3.f);               // c4
        acc = fmaf(acc, t, 1.5f);                     // c3
        acc = fmaf(acc, t, -1.f);                     // c2
        acc = fmaf(acc, t, 1.f);                      // c1
        float pp = t * acc;
        q[j] = pp;
        S1 += pp;
        S2 += pp * fmaf(pp, pp - 1.f, 1.f);           // p - p^2 + p^3 ~ p/(1+p)
    }
    S1 = wave_sum(S1); S2 = wave_sum(S2);
    float f = S1 - 1.f;
    float tmax = qm * s;

    if ((tmax < 0.22f) && (fabsf(f) < 0.05f)) {
        // ---- typical: one scalar Newton step, linear per-element correction ----
        float dsig = -__fdividef(f, S2);
#pragma unroll
        for (int j = 0; j < EPL; ++j) {
            float pp = q[j];
            float rr = pp * fmaf(pp, pp - 1.f, 1.f);
            q[j] = fmaf(rr, dsig, pp);
        }
    } else {
        // ---- rare heavy rows (~2%): re-derive t from global (L2-hot), robust Halley ----
        float ls = __log2f(s);
#pragma unroll
        for (int j = 0; j < 16; ++j) {
            float4 v = x4[lane + j * 64];
#pragma unroll
            for (int k = 0; k < 4; ++k) {
                float xv = (k == 0) ? v.x : (k == 1) ? v.y : (k == 2) ? v.z : v.w;
                float t = __builtin_amdgcn_exp2f(fmaf(xv, C2E, ls));
                q[4 * j + k] = __logf(1.f + t);       // upper bound on W(t)
            }
        }
        for (int it = 0; it < 10; ++it) {
            S1 = 0.f; S2 = 0.f;
            float ls2 = __log2f(s);
#pragma unroll
            for (int j = 0; j < 16; ++j) {
                float4 v = x4[lane + j * 64];
#pragma unroll
                for (int k = 0; k < 4; ++k) {
                    float xv = (k == 0) ? v.x : (k == 1) ? v.y : (k == 2) ? v.z : v.w;
                    float t = __builtin_amdgcn_exp2f(fmaf(xv, C2E, ls2));
                    float pp = halley_hw(q[4 * j + k], t);
                    pp = halley_hw(pp, t);
                    q[4 * j + k] = pp;
                    S1 += pp;
                    S2 += __fdividef(pp, 1.f + pp);
                }
            }
            S1 = wave_sum(S1); S2 = wave_sum(S2);
            f = S1 - 1.f;
            if (fabsf(f) < 2e-5f) break;              // wave-uniform
            float dsig = fminf(fmaxf(-__fdividef(f, S2), -1.f), 1.f);
            s *= __expf(dsig);
        }
    }

    // ---- store (non-temporal stream) ----
#pragma unroll
    for (int j = 0; j < 16; ++j) {
        vfloat4 v;
        v.x = q[4 * j + 0]; v.y = q[4 * j + 1];
        v.z = q[4 * j + 2]; v.w = q[4 * j + 3];
        __builtin_nontemporal_store(v, &p4[lane + j * 64]);
    }
}

extern "C" void kernel_launch(void* const* d_in, const int* in_sizes, int n_in,
                              void* d_out, int out_size, void* d_ws, size_t ws_size,
                              hipStream_t stream) {
    const float* x = (const float*)d_in[0];
    float* out = (float*)d_out;
    int rows = out_size / COLS;
    int blocks = (rows + WPB - 1) / WPB;
    prox_softmax_kernel<<<blocks, TPB, 0, stream>>>(x, out, rows);
}

// Round 9
// 56.472 us; speedup vs baseline: 1.4063x; 1.4063x over previous
//
#include <hip/hip_runtime.h>
#include <math.h>

#define TPB 256
#define NWAVE 4
#define EPT 16
#define COLS 4096
#define RPB 4   // rows per block (grid-stride, prefetched)

typedef float vfloat4 __attribute__((ext_vector_type(4)));

__device__ __forceinline__ float wave_sum(float v) {
#pragma unroll
    for (int o = 32; o > 0; o >>= 1) v += __shfl_xor(v, o, 64);
    return v;
}
__device__ __forceinline__ float wave_max(float v) {
#pragma unroll
    for (int o = 32; o > 0; o >>= 1) v = fmaxf(v, __shfl_xor(v, o, 64));
    return v;
}

// 2-barrier reduce for the rare heavy path (slots 20..27, reusable in a loop)
__device__ __forceinline__ void block_red2_h(float& a, float& b, volatile float* sred, int wid, int lane) {
    a = wave_sum(a); b = wave_sum(b);
    if (lane == 0) { sred[20 + wid] = a; sred[24 + wid] = b; }
    __syncthreads();
    a = (sred[20] + sred[21]) + (sred[22] + sred[23]);
    b = (sred[24] + sred[25]) + (sred[26] + sred[27]);
    __syncthreads();
}

// robust Halley step toward p = W(t), hardware exp (rare path only)
__device__ __forceinline__ float halley_hw(float p, float t) {
    float e = __expf(p);
    float w = p * e;
    float f = w - t;
    float fp = w + e;                                // (1+p)e
    float den = fmaf(fp, fp, -0.5f * f * (fp + e));  // fp^2 - 0.5 f (2+p)e
    return p - __fdividef(f * fp, den);
}

// Per row: p_i = W(e^{2(y_i+nu)-1}), nu s.t. sum p = 1   (alpha = 0.5)
__global__ __launch_bounds__(TPB) void prox_softmax_kernel(
    const float* __restrict__ X, float* __restrict__ P, int rows)
{
    __shared__ float sred[28];
    const int tid = threadIdx.x;
    const int wid = tid >> 6, lane = tid & 63;
    const int row0 = blockIdx.x * RPB;
    const float C2E = 2.8853900817779268f;  // 2/ln(2)

    float cur[EPT], nxt[EPT];

    // ---- load first row ----
    {
        const float4* __restrict__ x4 = reinterpret_cast<const float4*>(X + (size_t)row0 * COLS);
#pragma unroll
        for (int j = 0; j < 4; ++j) {
            float4 v = x4[tid + j * TPB];
            cur[4 * j + 0] = v.x; cur[4 * j + 1] = v.y;
            cur[4 * j + 2] = v.z; cur[4 * j + 3] = v.w;
        }
    }

    for (int r = 0; r < RPB; ++r) {
        const int row = row0 + r;
        if (row >= rows) return;
        const float4* __restrict__ x4 = reinterpret_cast<const float4*>(X + (size_t)row * COLS);
        vfloat4* __restrict__ p4 = reinterpret_cast<vfloat4*>(P + (size_t)row * COLS);

        // ---- prefetch next row (hide HBM latency under this row's compute) ----
        if (r + 1 < RPB && row + 1 < rows) {
            const float4* __restrict__ x4n = reinterpret_cast<const float4*>(X + (size_t)(row + 1) * COLS);
#pragma unroll
            for (int j = 0; j < 4; ++j) {
                float4 v = x4n[tid + j * TPB];
                nxt[4 * j + 0] = v.x; nxt[4 * j + 1] = v.y;
                nxt[4 * j + 2] = v.z; nxt[4 * j + 3] = v.w;
            }
        }

        // ---- exp pass: q = exp2(y*2/ln2); A = sum, B = sum^2, qm = max ----
        float A = 0.f, B = 0.f, qm = 0.f;
#pragma unroll
        for (int j = 0; j < EPT; ++j) {
            float e = __builtin_amdgcn_exp2f(cur[j] * C2E);
            cur[j] = e;
            A += e;
            B = fmaf(e, e, B);
            qm = fmaxf(qm, e);
        }

        // ---- reduction round 1 (single barrier, slots 0..11) ----
        A = wave_sum(A); B = wave_sum(B); qm = wave_max(qm);
        if (lane == 0) { sred[wid] = A; sred[4 + wid] = B; sred[8 + wid] = qm; }
        __syncthreads();
        A  = (sred[0] + sred[1]) + (sred[2] + sred[3]);
        B  = (sred[4] + sred[5]) + (sred[6] + sred[7]);
        qm = fmaxf(fmaxf(sred[8], sred[9]), fmaxf(sred[10], sred[11]));

        // ---- scalar init: s*A - s^2*B = 1, smaller root ----
        float disc = fmaf(A, A, -4.f * B);
        float s = __fdividef(2.f, A + sqrtf(fmaxf(disc, 0.f)));

        // ---- fast eval: W series thru t^7; S1 = sum p, S2 ~ sum p/(1+p) ----
        float S1 = 0.f, S2 = 0.f;
#pragma unroll
        for (int j = 0; j < EPT; ++j) {
            float t = cur[j] * s;
            float acc = fmaf(23.343054f, t, -10.8f);      // c7, c6
            acc = fmaf(acc, t, 125.f / 24.f);             // c5
            acc = fmaf(acc, t, -8.f / 3.f);               // c4
            acc = fmaf(acc, t, 1.5f);                     // c3
            acc = fmaf(acc, t, -1.f);                     // c2
            acc = fmaf(acc, t, 1.f);                      // c1
            float pp = t * acc;
            cur[j] = pp;
            S1 += pp;
            S2 += pp * fmaf(pp, pp - 1.f, 1.f);           // p - p^2 + p^3
        }

        // ---- reduction round 2 (single barrier, slots 12..19) ----
        S1 = wave_sum(S1); S2 = wave_sum(S2);
        if (lane == 0) { sred[12 + wid] = S1; sred[16 + wid] = S2; }
        __syncthreads();
        S1 = (sred[12] + sred[13]) + (sred[14] + sred[15]);
        S2 = (sred[16] + sred[17]) + (sred[18] + sred[19]);

        float f = S1 - 1.f;
        float tmax = qm * s;

        if ((tmax < 0.22f) && (fabsf(f) < 0.05f)) {
            // ---- typical: one scalar Newton step, linear per-element correction ----
            float dsig = -__fdividef(f, S2);
#pragma unroll
            for (int j = 0; j < EPT; ++j) {
                float pp = cur[j];
                float rr = pp * fmaf(pp, pp - 1.f, 1.f);
                cur[j] = fmaf(rr, dsig, pp);
            }
        } else {
            // ---- rare heavy row: reload y (L2-hot), robust hardware-exp Halley ----
            float ls = __log2f(s);
#pragma unroll
            for (int j = 0; j < 4; ++j) {
                float4 v = x4[tid + j * TPB];
#pragma unroll
                for (int k = 0; k < 4; ++k) {
                    float xv = (k == 0) ? v.x : (k == 1) ? v.y : (k == 2) ? v.z : v.w;
                    float t = __builtin_amdgcn_exp2f(fmaf(xv, C2E, ls));
                    cur[4 * j + k] = __logf(1.f + t);     // upper bound on W(t)
                }
            }
            for (int it = 0; it < 10; ++it) {
                S1 = 0.f; S2 = 0.f;
                float ls2 = __log2f(s);
#pragma unroll
                for (int j = 0; j < 4; ++j) {
                    float4 v = x4[tid + j * TPB];
#pragma unroll
                    for (int k = 0; k < 4; ++k) {
                        float xv = (k == 0) ? v.x : (k == 1) ? v.y : (k == 2) ? v.z : v.w;
                        float t = __builtin_amdgcn_exp2f(fmaf(xv, C2E, ls2));
                        float pp = halley_hw(cur[4 * j + k], t);
                        pp = halley_hw(pp, t);
                        cur[4 * j + k] = pp;
                        S1 += pp;
                        S2 += __fdividef(pp, 1.f + pp);
                    }
                }
                block_red2_h(S1, S2, sred, wid, lane);
                f = S1 - 1.f;
                if (fabsf(f) < 2e-5f) break;              // block-uniform
                float dsig = fminf(fmaxf(-__fdividef(f, S2), -1.f), 1.f);
                s *= __expf(dsig);
            }
        }

        // ---- store (non-temporal stream) ----
#pragma unroll
        for (int j = 0; j < 4; ++j) {
            vfloat4 v;
            v.x = cur[4 * j + 0]; v.y = cur[4 * j + 1];
            v.z = cur[4 * j + 2]; v.w = cur[4 * j + 3];
            __builtin_nontemporal_store(v, &p4[tid + j * TPB]);
        }

        // ---- rotate prefetched row in ----
        if (r + 1 < RPB) {
#pragma unroll
            for (int j = 0; j < EPT; ++j) cur[j] = nxt[j];
        }
    }
}

extern "C" void kernel_launch(void* const* d_in, const int* in_sizes, int n_in,
                              void* d_out, int out_size, void* d_ws, size_t ws_size,
                              hipStream_t stream) {
    const float* x = (const float*)d_in[0];
    float* out = (float*)d_out;
    int rows = out_size / COLS;
    int blocks = (rows + RPB - 1) / RPB;
    prox_softmax_kernel<<<blocks, TPB, 0, stream>>>(x, out, rows);
}

// Round 10
// 52.692 us; speedup vs baseline: 1.5072x; 1.0717x over previous
//
#include <hip/hip_runtime.h>
#include <math.h>

#define TPB 256
#define EPT 16
#define COLS 4096

typedef float vfloat4 __attribute__((ext_vector_type(4)));

__device__ __forceinline__ float wave_sum(float v) {
#pragma unroll
    for (int o = 32; o > 0; o >>= 1) v += __shfl_xor(v, o, 64);
    return v;
}
__device__ __forceinline__ float wave_max(float v) {
#pragma unroll
    for (int o = 32; o > 0; o >>= 1) v = fmaxf(v, __shfl_xor(v, o, 64));
    return v;
}

// robust Halley step toward p = W(t), hardware exp (rare path only)
__device__ __forceinline__ float halley_hw(float p, float t) {
    float e = __expf(p);
    float w = p * e;
    float f = w - t;
    float fp = w + e;                                // (1+p)e
    float den = fmaf(fp, fp, -0.5f * f * (fp + e));  // fp^2 - 0.5 f (2+p)e
    return p - __fdividef(f * fp, den);
}

// W series through t^7 (no divides)
__device__ __forceinline__ float w_series(float t) {
    float acc = fmaf(23.343054f, t, -10.8f);          // c7, c6
    acc = fmaf(acc, t, 125.f / 24.f);                 // c5
    acc = fmaf(acc, t, -8.f / 3.f);                   // c4
    acc = fmaf(acc, t, 1.5f);                         // c3
    acc = fmaf(acc, t, -1.f);                         // c2
    acc = fmaf(acc, t, 1.f);                          // c1
    return t * acc;
}

// rare heavy-row solve: reload y from global (L2/L3-hot), robust Halley + nu-Newton
__device__ __forceinline__ void heavy_solve(
    const float4* __restrict__ x4, float* qq, float& s,
    volatile float* sred, int tid, int wid, int lane, float C2E)
{
    float ls = __log2f(s);
#pragma unroll
    for (int j = 0; j < 4; ++j) {
        float4 v = x4[tid + j * TPB];
#pragma unroll
        for (int k = 0; k < 4; ++k) {
            float xv = (k == 0) ? v.x : (k == 1) ? v.y : (k == 2) ? v.z : v.w;
            float t = __builtin_amdgcn_exp2f(fmaf(xv, C2E, ls));
            qq[4 * j + k] = __logf(1.f + t);          // upper bound on W(t)
        }
    }
    for (int it = 0; it < 10; ++it) {
        float S1 = 0.f, S2 = 0.f;
        float ls2 = __log2f(s);
#pragma unroll
        for (int j = 0; j < 4; ++j) {
            float4 v = x4[tid + j * TPB];
#pragma unroll
            for (int k = 0; k < 4; ++k) {
                float xv = (k == 0) ? v.x : (k == 1) ? v.y : (k == 2) ? v.z : v.w;
                float t = __builtin_amdgcn_exp2f(fmaf(xv, C2E, ls2));
                float pp = halley_hw(qq[4 * j + k], t);
                pp = halley_hw(pp, t);
                qq[4 * j + k] = pp;
                S1 += pp;
                S2 += __fdividef(pp, 1.f + pp);
            }
        }
        S1 = wave_sum(S1); S2 = wave_sum(S2);
        if (lane == 0) { sred[40 + wid] = S1; sred[44 + wid] = S2; }
        __syncthreads();
        S1 = (sred[40] + sred[41]) + (sred[42] + sred[43]);
        S2 = (sred[44] + sred[45]) + (sred[46] + sred[47]);
        __syncthreads();
        float f = S1 - 1.f;
        if (fabsf(f) < 2e-5f) break;                  // block-uniform
        float dsig = fminf(fmaxf(-__fdividef(f, S2), -1.f), 1.f);
        s *= __expf(dsig);
    }
}

// Per row: p_i = W(e^{2(y_i+nu)-1}), nu s.t. sum p = 1   (alpha = 0.5)
// Two independent rows per block: dependency chains interleave (ILP), barriers shared.
__global__ __launch_bounds__(TPB) void prox_softmax_kernel(
    const float* __restrict__ X, float* __restrict__ P, int rows)
{
    __shared__ float sred[48];
    const int tid = threadIdx.x;
    const int wid = tid >> 6, lane = tid & 63;
    const int row0 = blockIdx.x * 2;
    const int row1 = row0 + 1;
    const float C2E = 2.8853900817779268f;  // 2/ln(2)

    const float4* __restrict__ xa = reinterpret_cast<const float4*>(X + (size_t)row0 * COLS);
    const float4* __restrict__ xb = reinterpret_cast<const float4*>(X + (size_t)row1 * COLS);
    vfloat4* __restrict__ pa = reinterpret_cast<vfloat4*>(P + (size_t)row0 * COLS);
    vfloat4* __restrict__ pb = reinterpret_cast<vfloat4*>(P + (size_t)row1 * COLS);

    float a[EPT], b[EPT];

    // ---- load both rows (coalesced float4; 8 independent loads in flight) ----
#pragma unroll
    for (int j = 0; j < 4; ++j) {
        float4 va = xa[tid + j * TPB];
        float4 vb = xb[tid + j * TPB];
        a[4 * j + 0] = va.x; a[4 * j + 1] = va.y; a[4 * j + 2] = va.z; a[4 * j + 3] = va.w;
        b[4 * j + 0] = vb.x; b[4 * j + 1] = vb.y; b[4 * j + 2] = vb.z; b[4 * j + 3] = vb.w;
    }

    // ---- exp pass both rows: q = exp2(y*2/ln2); moments A,B + max, two chains ----
    float A0 = 0.f, B0 = 0.f, m0 = 0.f;
    float A1 = 0.f, B1 = 0.f, m1 = 0.f;
#pragma unroll
    for (int j = 0; j < EPT; ++j) {
        float e0 = __builtin_amdgcn_exp2f(a[j] * C2E);
        float e1 = __builtin_amdgcn_exp2f(b[j] * C2E);
        a[j] = e0; b[j] = e1;
        A0 += e0;             A1 += e1;
        B0 = fmaf(e0, e0, B0); B1 = fmaf(e1, e1, B1);
        m0 = fmaxf(m0, e0);   m1 = fmaxf(m1, e1);
    }

    // ---- reduction round 1: 6 interleaved butterflies, ONE barrier ----
    A0 = wave_sum(A0); A1 = wave_sum(A1);
    B0 = wave_sum(B0); B1 = wave_sum(B1);
    m0 = wave_max(m0); m1 = wave_max(m1);
    if (lane == 0) {
        sred[wid] = A0;      sred[4 + wid] = B0;  sred[8 + wid] = m0;
        sred[12 + wid] = A1; sred[16 + wid] = B1; sred[20 + wid] = m1;
    }
    __syncthreads();
    A0 = (sred[0] + sred[1]) + (sred[2] + sred[3]);
    B0 = (sred[4] + sred[5]) + (sred[6] + sred[7]);
    m0 = fmaxf(fmaxf(sred[8], sred[9]), fmaxf(sred[10], sred[11]));
    A1 = (sred[12] + sred[13]) + (sred[14] + sred[15]);
    B1 = (sred[16] + sred[17]) + (sred[18] + sred[19]);
    m1 = fmaxf(fmaxf(sred[20], sred[21]), fmaxf(sred[22], sred[23]));

    // ---- scalar inits: s*A - s^2*B = 1, smaller root (two independent) ----
    float s0 = __fdividef(2.f, A0 + sqrtf(fmaxf(fmaf(A0, A0, -4.f * B0), 0.f)));
    float s1 = __fdividef(2.f, A1 + sqrtf(fmaxf(fmaf(A1, A1, -4.f * B1), 0.f)));

    // ---- series pass both rows; S1 = sum p, S2 ~ sum p/(1+p) ----
    float Sa = 0.f, Ta = 0.f, Sb = 0.f, Tb = 0.f;
#pragma unroll
    for (int j = 0; j < EPT; ++j) {
        float p0 = w_series(a[j] * s0);
        float p1 = w_series(b[j] * s1);
        a[j] = p0; b[j] = p1;
        Sa += p0; Sb += p1;
        Ta += p0 * fmaf(p0, p0 - 1.f, 1.f);
        Tb += p1 * fmaf(p1, p1 - 1.f, 1.f);
    }

    // ---- reduction round 2: 4 interleaved butterflies, ONE barrier ----
    Sa = wave_sum(Sa); Sb = wave_sum(Sb);
    Ta = wave_sum(Ta); Tb = wave_sum(Tb);
    if (lane == 0) {
        sred[24 + wid] = Sa; sred[28 + wid] = Ta;
        sred[32 + wid] = Sb; sred[36 + wid] = Tb;
    }
    __syncthreads();
    Sa = (sred[24] + sred[25]) + (sred[26] + sred[27]);
    Ta = (sred[28] + sred[29]) + (sred[30] + sred[31]);
    Sb = (sred[32] + sred[33]) + (sred[34] + sred[35]);
    Tb = (sred[36] + sred[37]) + (sred[38] + sred[39]);

    float f0 = Sa - 1.f, f1 = Sb - 1.f;

    // ---- row0 finish (block-uniform branch) ----
    if ((m0 * s0 < 0.22f) && (fabsf(f0) < 0.05f)) {
        float dsig = -__fdividef(f0, Ta);
#pragma unroll
        for (int j = 0; j < EPT; ++j) {
            float pp = a[j];
            a[j] = fmaf(pp * fmaf(pp, pp - 1.f, 1.f), dsig, pp);
        }
    } else {
        __syncthreads();
        heavy_solve(xa, a, s0, sred, tid, wid, lane, C2E);
    }
    // ---- row1 finish (block-uniform branch) ----
    if ((m1 * s1 < 0.22f) && (fabsf(f1) < 0.05f)) {
        float dsig = -__fdividef(f1, Tb);
#pragma unroll
        for (int j = 0; j < EPT; ++j) {
            float pp = b[j];
            b[j] = fmaf(pp * fmaf(pp, pp - 1.f, 1.f), dsig, pp);
        }
    } else {
        __syncthreads();
        heavy_solve(xb, b, s1, sred, tid, wid, lane, C2E);
    }

    // ---- store both rows (non-temporal stream) ----
#pragma unroll
    for (int j = 0; j < 4; ++j) {
        vfloat4 v0, v1;
        v0.x = a[4 * j + 0]; v0.y = a[4 * j + 1]; v0.z = a[4 * j + 2]; v0.w = a[4 * j + 3];
        v1.x = b[4 * j + 0]; v1.y = b[4 * j + 1]; v1.z = b[4 * j + 2]; v1.w = b[4 * j + 3];
        __builtin_nontemporal_store(v0, &pa[tid + j * TPB]);
        __builtin_nontemporal_store(v1, &pb[tid + j * TPB]);
    }
}

extern "C" void kernel_launch(void* const* d_in, const int* in_sizes, int n_in,
                              void* d_out, int out_size, void* d_ws, size_t ws_size,
                              hipStream_t stream) {
    const float* x = (const float*)d_in[0];
    float* out = (float*)d_out;
    int rows = out_size / COLS;
    int blocks = rows / 2;
    prox_softmax_kernel<<<blocks, TPB, 0, stream>>>(x, out, rows);
}

// Round 11
// 50.840 us; speedup vs baseline: 1.5621x; 1.0364x over previous
//
#include <hip/hip_runtime.h>
#include <math.h>

#define TPB 256
#define EPT 16
#define COLS 4096

typedef float vfloat4 __attribute__((ext_vector_type(4)));

__device__ __forceinline__ float wave_sum(float v) {
#pragma unroll
    for (int o = 32; o > 0; o >>= 1) v += __shfl_xor(v, o, 64);
    return v;
}
__device__ __forceinline__ float wave_max(float v) {
#pragma unroll
    for (int o = 32; o > 0; o >>= 1) v = fmaxf(v, __shfl_xor(v, o, 64));
    return v;
}

// robust Halley step toward p = W(t), hardware exp (rare path only)
__device__ __forceinline__ float halley_hw(float p, float t) {
    float e = __expf(p);
    float w = p * e;
    float f = w - t;
    float fp = w + e;                                // (1+p)e
    float den = fmaf(fp, fp, -0.5f * f * (fp + e));  // fp^2 - 0.5 f (2+p)e
    return p - __fdividef(f * fp, den);
}

// Per row: p_i = W(e^{2(y_i+nu)-1}), nu s.t. sum p = 1   (alpha = 0.5)
// One row per 256-thread block; 2 barriers total in the fast path.
__global__ __launch_bounds__(TPB) void prox_softmax_kernel(
    const float* __restrict__ X, float* __restrict__ P, int rows)
{
    __shared__ float sred[28];
    const int tid = threadIdx.x;
    const int wid = tid >> 6, lane = tid & 63;
    const int row = blockIdx.x;
    if (row >= rows) return;
    const float C2E = 2.8853900817779268f;  // 2/ln(2)

    const float4* __restrict__ x4 = reinterpret_cast<const float4*>(X + (size_t)row * COLS);
    vfloat4* __restrict__ p4 = reinterpret_cast<vfloat4*>(P + (size_t)row * COLS);

    float q[EPT];

    // ---- load row (coalesced float4) ----
#pragma unroll
    for (int j = 0; j < 4; ++j) {
        float4 v = x4[tid + j * TPB];
        q[4 * j + 0] = v.x; q[4 * j + 1] = v.y;
        q[4 * j + 2] = v.z; q[4 * j + 3] = v.w;
    }

    // ---- exp pass: q = exp2(y*2/ln2); A = sum, B = sum sq, qm = max ----
    float A = 0.f, B = 0.f, qm = 0.f;
#pragma unroll
    for (int j = 0; j < EPT; ++j) {
        float e = __builtin_amdgcn_exp2f(q[j] * C2E);
        q[j] = e;
        A += e;
        B = fmaf(e, e, B);
        qm = fmaxf(qm, e);
    }

    // ---- reduction round 1: ONE barrier (slots 0..11) ----
    A = wave_sum(A); B = wave_sum(B); qm = wave_max(qm);
    if (lane == 0) { sred[wid] = A; sred[4 + wid] = B; sred[8 + wid] = qm; }
    __syncthreads();
    A  = (sred[0] + sred[1]) + (sred[2] + sred[3]);
    B  = (sred[4] + sred[5]) + (sred[6] + sred[7]);
    qm = fmaxf(fmaxf(sred[8], sred[9]), fmaxf(sred[10], sred[11]));

    // ---- scalar init: s*A - s^2*B = 1 (W series thru t^2), smaller root ----
    float disc = fmaf(A, A, -4.f * B);
    float s = __fdividef(2.f, A + sqrtf(fmaxf(disc, 0.f)));

    // ---- fast eval: W series thru t^7 (no divides); S1 = sum p, S2 ~ sum p/(1+p) ----
    float S1 = 0.f, S2 = 0.f;
#pragma unroll
    for (int j = 0; j < EPT; ++j) {
        float t = q[j] * s;
        float acc = fmaf(23.343054f, t, -10.8f);      // c7, c6
        acc = fmaf(acc, t, 125.f / 24.f);             // c5
        acc = fmaf(acc, t, -8.f / 3.f);               // c4
        acc = fmaf(acc, t, 1.5f);                     // c3
        acc = fmaf(acc, t, -1.f);                     // c2
        acc = fmaf(acc, t, 1.f);                      // c1
        float pp = t * acc;
        q[j] = pp;
        S1 += pp;
        S2 += pp * fmaf(pp, pp - 1.f, 1.f);           // p - p^2 + p^3
    }

    // ---- reduction round 2: ONE barrier (slots 12..19) ----
    S1 = wave_sum(S1); S2 = wave_sum(S2);
    if (lane == 0) { sred[12 + wid] = S1; sred[16 + wid] = S2; }
    __syncthreads();
    S1 = (sred[12] + sred[13]) + (sred[14] + sred[15]);
    S2 = (sred[16] + sred[17]) + (sred[18] + sred[19]);

    float f = S1 - 1.f;
    float tmax = qm * s;

    if ((tmax < 0.22f) && (fabsf(f) < 0.05f)) {
        // ---- typical: one scalar Newton step, linear per-element correction ----
        float dsig = -__fdividef(f, S2);
#pragma unroll
        for (int j = 0; j < EPT; ++j) {
            float pp = q[j];
            float rr = pp * fmaf(pp, pp - 1.f, 1.f);
            q[j] = fmaf(rr, dsig, pp);
        }
    } else {
        // ---- rare heavy row: reload y (L2/L3-hot), robust hardware-exp Halley ----
        float ls = __log2f(s);
#pragma unroll
        for (int j = 0; j < 4; ++j) {
            float4 v = x4[tid + j * TPB];
#pragma unroll
            for (int k = 0; k < 4; ++k) {
                float xv = (k == 0) ? v.x : (k == 1) ? v.y : (k == 2) ? v.z : v.w;
                float t = __builtin_amdgcn_exp2f(fmaf(xv, C2E, ls));
                q[4 * j + k] = __logf(1.f + t);       // upper bound on W(t)
            }
        }
        for (int it = 0; it < 10; ++it) {
            S1 = 0.f; S2 = 0.f;
            float ls2 = __log2f(s);
#pragma unroll
            for (int j = 0; j < 4; ++j) {
                float4 v = x4[tid + j * TPB];
#pragma unroll
                for (int k = 0; k < 4; ++k) {
                    float xv = (k == 0) ? v.x : (k == 1) ? v.y : (k == 2) ? v.z : v.w;
                    float t = __builtin_amdgcn_exp2f(fmaf(xv, C2E, ls2));
                    float pp = halley_hw(q[4 * j + k], t);
                    pp = halley_hw(pp, t);
                    q[4 * j + k] = pp;
                    S1 += pp;
                    S2 += __fdividef(pp, 1.f + pp);
                }
            }
            S1 = wave_sum(S1); S2 = wave_sum(S2);
            if (lane == 0) { sred[20 + wid] = S1; sred[24 + wid] = S2; }
            __syncthreads();
            S1 = (sred[20] + sred[21]) + (sred[22] + sred[23]);
            S2 = (sred[24] + sred[25]) + (sred[26] + sred[27]);
            __syncthreads();
            f = S1 - 1.f;
            if (fabsf(f) < 2e-5f) break;              // block-uniform
            float dsig = fminf(fmaxf(-__fdividef(f, S2), -1.f), 1.f);
            s *= __expf(dsig);
        }
    }

    // ---- store (non-temporal stream) ----
#pragma unroll
    for (int j = 0; j < 4; ++j) {
        vfloat4 v;
        v.x = q[4 * j + 0]; v.y = q[4 * j + 1];
        v.z = q[4 * j + 2]; v.w = q[4 * j + 3];
        __builtin_nontemporal_store(v, &p4[tid + j * TPB]);
    }
}

extern "C" void kernel_launch(void* const* d_in, const int* in_sizes, int n_in,
                              void* d_out, int out_size, void* d_ws, size_t ws_size,
                              hipStream_t stream) {
    const float* x = (const float*)d_in[0];
    float* out = (float*)d_out;
    int rows = out_size / COLS;
    prox_softmax_kernel<<<rows, TPB, 0, stream>>>(x, out, rows);
}